// Round 1
// baseline (821.842 us; speedup 1.0000x reference)
//
#include <hip/hip_runtime.h>
#include <hip/hip_bf16.h>
#include <math.h>

typedef __attribute__((ext_vector_type(4))) float f32x4;
typedef __attribute__((ext_vector_type(8))) short s16x8;
typedef __attribute__((ext_vector_type(4))) short s16x4;

#define BB 4
#define TT 2048
#define CC 2048
#define NHEAD 16
#define KVH 4
#define HD 128
#define BT (BB*TT)      // 8192
#define NHC 2048        // N*H
#define KHC 512         // K*H
#define QKVC 3072

__device__ __forceinline__ float bf2f(unsigned short u) {
  union { unsigned u; float f; } v; v.u = ((unsigned)u) << 16; return v.f;
}
__device__ __forceinline__ unsigned short f2bf(float f) {
  union { float f; unsigned u; } v; v.f = f;
  unsigned r = v.u + 0x7fff + ((v.u >> 16) & 1);
  return (unsigned short)(r >> 16);
}

#if defined(__has_builtin)
#if __has_builtin(__builtin_amdgcn_exp2f)
#define EXP2F(x) __builtin_amdgcn_exp2f(x)
#endif
#endif
#ifndef EXP2F
#define EXP2F(x) exp2f(x)
#endif

// ---- async global->LDS 16B (lane i lands at ldsbase + i*16; ldsbase must be wave-uniform) ----
__device__ __forceinline__ void glld16(const void* gsrc, void* ldsbase) {
  __builtin_amdgcn_global_load_lds(
      (const __attribute__((address_space(1))) unsigned int*)gsrc,
      (__attribute__((address_space(3))) unsigned int*)(unsigned int)(unsigned long long)ldsbase,
      16, 0, 0);
}

// ---------------- fp32 -> bf16 elementwise ----------------
__global__ void cvt_f2b(const float* __restrict__ in, unsigned short* __restrict__ out, int n4) {
  int i = blockIdx.x * 256 + threadIdx.x;
  if (i >= n4) return;
  float4 v = ((const float4*)in)[i];
  ushort4 o;
  o.x = f2bf(v.x); o.y = f2bf(v.y); o.z = f2bf(v.z); o.w = f2bf(v.w);
  ((ushort4*)out)[i] = o;
}

// ---------------- fp32 [R][Cc] -> bf16 [Cc][R] transpose ----------------
__global__ void trans_f2b(const float* __restrict__ in, unsigned short* __restrict__ out, int R, int Cc) {
  __shared__ float tile[32][33];
  int c0 = blockIdx.x * 32, r0 = blockIdx.y * 32;
  int tx = threadIdx.x, ty = threadIdx.y;
  #pragma unroll
  for (int k = 0; k < 4; k++)
    tile[ty + 8*k][tx] = in[(size_t)(r0 + ty + 8*k) * Cc + c0 + tx];
  __syncthreads();
  #pragma unroll
  for (int k = 0; k < 4; k++)
    out[(size_t)(c0 + ty + 8*k) * R + r0 + tx] = f2bf(tile[tx][ty + 8*k]);
}

// ---------------- V slice transpose bf16 [s][h] -> [h][s] ----------------
__global__ void trans_v(const unsigned short* __restrict__ qkv, unsigned short* __restrict__ vT) {
  __shared__ unsigned short tile[32][33];
  int slice = blockIdx.z;           // b*4+kh
  int s0 = blockIdx.x * 32, h0 = blockIdx.y * 32;
  int tx = threadIdx.x, ty = threadIdx.y;
  const unsigned short* in = qkv + (size_t)(slice >> 2) * TT * QKVC + (NHC + KHC) + (slice & 3) * HD;
  unsigned short* out = vT + (size_t)slice * HD * TT;
  #pragma unroll
  for (int k = 0; k < 4; k++)
    tile[ty + 8*k][tx] = in[(size_t)(s0 + ty + 8*k) * QKVC + h0 + tx];
  __syncthreads();
  #pragma unroll
  for (int k = 0; k < 4; k++)
    out[(size_t)(h0 + ty + 8*k) * TT + s0 + tx] = tile[tx][ty + 8*k];
}

// ---------------- RoPE sin/cos table (fp64 precision) ----------------
__global__ void sincos_init(float* __restrict__ stab, float* __restrict__ ctab) {
  int idx = blockIdx.x * 256 + threadIdx.x;
  if (idx >= TT * 64) return;
  int t = idx >> 6, i = idx & 63;
  double inv = exp(-log(10000.0) * ((double)i / 64.0));
  double ang = (double)t * inv;
  stab[idx] = (float)sin(ang);
  ctab[idx] = (float)cos(ang);
}

// ---------------- NT GEMM: C[M][Nn] = A[M][Kd] * Bt[Nn][Kd]^T ----------------
// m97-style: global_load_lds dwordx4 staging, 128x128 tile, BK=32, 16 MFMA/wave/iter.
template<int OUTBF16>
__global__ __launch_bounds__(256) void gemm_nt(
    const unsigned short* __restrict__ A, const unsigned short* __restrict__ Bt,
    void* __restrict__ outp, int M, int Nn, int Kd) {
  __shared__ unsigned short As[128 * 32];
  __shared__ unsigned short Bs[128 * 32];
  int tid = threadIdx.x;
  int wave = tid >> 6, lane = tid & 63, q4 = lane >> 4, l16 = lane & 15;
  int m0 = blockIdx.y * 128, n0 = blockIdx.x * 128;
  int wm = (wave & 1) * 64, wn = (wave >> 1) * 64;
  f32x4 acc[4][4];
  #pragma unroll
  for (int i = 0; i < 4; i++)
    #pragma unroll
    for (int j = 0; j < 4; j++) acc[i][j] = f32x4{0.f, 0.f, 0.f, 0.f};

  int r0s = wave * 32 + (lane >> 2);
  int r1s = r0s + 16;
  int cg0 = (lane & 3) ^ ((r0s >> 1) & 3);
  int cg1 = (lane & 3) ^ ((r1s >> 1) & 3);
  const unsigned short* Ag0 = A + (size_t)(m0 + r0s) * Kd + cg0 * 8;
  const unsigned short* Ag1 = A + (size_t)(m0 + r1s) * Kd + cg1 * 8;
  const unsigned short* Bg0 = Bt + (size_t)(n0 + r0s) * Kd + cg0 * 8;
  const unsigned short* Bg1 = Bt + (size_t)(n0 + r1s) * Kd + cg1 * 8;
  unsigned short* lA0 = As + (wave * 2 + 0) * 512;
  unsigned short* lA1 = As + (wave * 2 + 1) * 512;
  unsigned short* lB0 = Bs + (wave * 2 + 0) * 512;
  unsigned short* lB1 = Bs + (wave * 2 + 1) * 512;

  int aoff[4], boff[4];
  #pragma unroll
  for (int f = 0; f < 4; f++) {
    int Ra = wm + f * 16 + l16;
    int Rb = wn + f * 16 + l16;
    aoff[f] = Ra * 32 + (q4 ^ ((Ra >> 1) & 3)) * 8;
    boff[f] = Rb * 32 + (q4 ^ ((Rb >> 1) & 3)) * 8;
  }

  for (int k0 = 0; k0 < Kd; k0 += 32) {
    __syncthreads();
    glld16(Ag0 + k0, lA0);
    glld16(Ag1 + k0, lA1);
    glld16(Bg0 + k0, lB0);
    glld16(Bg1 + k0, lB1);
    asm volatile("s_waitcnt vmcnt(0)" ::: "memory");
    __syncthreads();
    s16x8 af[4], bfr[4];
    #pragma unroll
    for (int mf = 0; mf < 4; mf++) af[mf] = *(const s16x8*)&As[aoff[mf]];
    #pragma unroll
    for (int nf = 0; nf < 4; nf++) bfr[nf] = *(const s16x8*)&Bs[boff[nf]];
    #pragma unroll
    for (int mf = 0; mf < 4; mf++)
      #pragma unroll
      for (int nf = 0; nf < 4; nf++)
        acc[mf][nf] = __builtin_amdgcn_mfma_f32_16x16x32_bf16(af[mf], bfr[nf], acc[mf][nf], 0, 0, 0);
  }
  #pragma unroll
  for (int mf = 0; mf < 4; mf++)
    #pragma unroll
    for (int nf = 0; nf < 4; nf++)
      #pragma unroll
      for (int r = 0; r < 4; r++) {
        int row = m0 + wm + mf*16 + q4*4 + r;
        int col = n0 + wn + nf*16 + l16;
        float v = acc[mf][nf][r];
        if (OUTBF16) ((unsigned short*)outp)[(size_t)row * Nn + col] = f2bf(v);
        else         ((float*)outp)[(size_t)row * Nn + col] = v;
      }
}

// ---------------- RMSNorm + RoPE + scale ----------------
// NOTE: q scale folds in log2(e) so attention can use exp2 directly
// (softmax is exactly invariant: p = exp(S-m) = 2^(S*log2e - m*log2e)).
__global__ __launch_bounds__(256) void postproc(
    const unsigned short* __restrict__ qkv, unsigned short* __restrict__ qr,
    unsigned short* __restrict__ kr, const float* __restrict__ stab, const float* __restrict__ ctab) {
  __shared__ float sh[NHC + KHC];
  __shared__ float redq[4], redk[4];
  int row = blockIdx.x;
  int t = row & (TT - 1);
  int tid = threadIdx.x;
  const unsigned short* base = qkv + (size_t)row * QKVC;
  float sq = 0.f, sk = 0.f;
  uint4 qv = *(const uint4*)&base[tid * 8];
  const unsigned short* qp = (const unsigned short*)&qv;
  #pragma unroll
  for (int i = 0; i < 8; i++) { float f = bf2f(qp[i]); sh[tid*8 + i] = f; sq += f*f; }
  unsigned kv = *(const unsigned*)&base[NHC + tid*2];
  {
    float f0 = bf2f((unsigned short)(kv & 0xffff));
    float f1 = bf2f((unsigned short)(kv >> 16));
    sh[NHC + tid*2] = f0; sh[NHC + tid*2 + 1] = f1;
    sk += f0*f0 + f1*f1;
  }
  #pragma unroll
  for (int off = 32; off > 0; off >>= 1) { sq += __shfl_xor(sq, off); sk += __shfl_xor(sk, off); }
  if ((tid & 63) == 0) { redq[tid >> 6] = sq; redk[tid >> 6] = sk; }
  __syncthreads();
  float fq = rsqrtf((redq[0]+redq[1]+redq[2]+redq[3]) * (1.f/NHC) + 1e-6f)
             * (0.08838834764831845f * 1.4426950408889634f);
  float fk = rsqrtf((redk[0]+redk[1]+redk[2]+redk[3]) * (1.f/KHC) + 1e-6f);
  #pragma unroll
  for (int pi = 0; pi < 4; pi++) {
    int P = pi * 256 + tid;
    int head = P >> 6, i = P & 63;
    float s = stab[t*64 + i], c = ctab[t*64 + i];
    float x1 = sh[head*128 + i], x2 = sh[head*128 + i + 64];
    qr[(size_t)row * NHC + head*128 + i]      = f2bf((x1*c - x2*s) * fq);
    qr[(size_t)row * NHC + head*128 + i + 64] = f2bf((x2*c + x1*s) * fq);
  }
  {
    int head = tid >> 6, i = tid & 63;
    float s = stab[t*64 + i], c = ctab[t*64 + i];
    float x1 = sh[NHC + head*128 + i], x2 = sh[NHC + head*128 + i + 64];
    kr[(size_t)row * KHC + head*128 + i]      = f2bf((x1*c - x2*s) * fk);
    kr[(size_t)row * KHC + head*128 + i + 64] = f2bf((x2*c + x1*s) * fk);
  }
}

// ---------------- flash attention v3 ----------------
// Changes vs v2:
//  - PV step uses mfma_f32_16x16x32 (K=32): vf/pf built as concat of the two
//    K=16 fragments with IDENTICAL (lane,reg)->s maps on A and B sides, so the
//    contraction is exact under any HW k-slot permutation. 128 -> 64 PV MFMA.
//  - T14 async-STAGE: next K/V tile prefetched into 16 uint4 regs during
//    compute; only the LDS write sits between the barriers.
//  - T5 setprio(1) around both MFMA clusters.
//  - exp2-domain softmax (log2e pre-folded into q scale by postproc).
__global__ __launch_bounds__(256, 2) void attn(
    const unsigned short* __restrict__ qr, const unsigned short* __restrict__ kr,
    const unsigned short* __restrict__ vT, unsigned short* __restrict__ enc) {
  __shared__ unsigned short Ks[128 * 128];
  __shared__ unsigned short Vs[128 * 128];
  int tid = threadIdx.x;
  int wave = tid >> 6, lane = tid & 63, q4 = lane >> 4, l16 = lane & 15;
  int bid = blockIdx.x;
  int qt = bid & 15, n = (bid >> 4) & 15, b = bid >> 8, kh = n >> 2;

  // staging geometry: thread handles rows tr + c2*16, 16B column chunk tc
  int tr = tid >> 4, tc = tid & 15;
  int sw = (tc ^ (tr & 7)) << 3;   // swizzled short-offset within row (r&7 == tr&7)
  const unsigned short* kp0 = kr + ((size_t)(b * TT)) * KHC + kh * HD + (size_t)tr * KHC + tc * 8;
  const unsigned short* vp0 = vT + ((size_t)((b * KVH + kh) * HD)) * TT + (size_t)tr * TT + tc * 8;

  // prefetch K/V tile 0 into registers
  uint4 kreg[8], vreg[8];
  #pragma unroll
  for (int c2 = 0; c2 < 8; c2++) {
    kreg[c2] = *(const uint4*)&kp0[(size_t)c2 * 16 * KHC];
    vreg[c2] = *(const uint4*)&vp0[(size_t)c2 * 16 * TT];
  }

  // Q tile -> Ks (swizzled), then q fragments to regs
  {
    const unsigned short* qp = qr + ((size_t)(b * TT + qt * 128)) * NHC + n * HD
                               + (size_t)tr * NHC + tc * 8;
    #pragma unroll
    for (int c2 = 0; c2 < 8; c2++)
      *(uint4*)&Ks[(c2 * 16 + tr) * 128 + sw] = *(const uint4*)&qp[(size_t)c2 * 16 * NHC];
  }
  __syncthreads();
  s16x8 qf[2][4];
  #pragma unroll
  for (int qb = 0; qb < 2; qb++)
    #pragma unroll
    for (int ku = 0; ku < 4; ku++) {
      int r = wave * 32 + qb * 16 + l16;
      qf[qb][ku] = *(const s16x8*)&Ks[r * 128 + (((ku * 4 + q4) ^ (r & 7)) << 3)];
    }

  float m_st[2] = {-1e30f, -1e30f}, l_st[2] = {0.f, 0.f};
  f32x4 O[2][8];
  #pragma unroll
  for (int qb = 0; qb < 2; qb++)
    #pragma unroll
    for (int hb = 0; hb < 8; hb++) O[qb][hb] = f32x4{0.f, 0.f, 0.f, 0.f};

  for (int j = 0; j < 16; j++) {
    __syncthreads();
    // write prefetched tile j to LDS
    #pragma unroll
    for (int c2 = 0; c2 < 8; c2++) {
      *(uint4*)&Ks[(c2 * 16 + tr) * 128 + sw] = kreg[c2];
      *(uint4*)&Vs[(c2 * 16 + tr) * 128 + sw] = vreg[c2];
    }
    __syncthreads();
    // issue prefetch for tile j+1; latency hides under QK+softmax+PV
    if (j < 15) {
      const unsigned short* kp = kp0 + (size_t)(j + 1) * 128 * KHC;
      const unsigned short* vp = vp0 + (size_t)(j + 1) * 128;
      #pragma unroll
      for (int c2 = 0; c2 < 8; c2++) {
        kreg[c2] = *(const uint4*)&kp[(size_t)c2 * 16 * KHC];
        vreg[c2] = *(const uint4*)&vp[(size_t)c2 * 16 * TT];
      }
    }
    // ---- QK^T (S^T layout) ----
    f32x4 S[2][8];
    #pragma unroll
    for (int qb = 0; qb < 2; qb++)
      #pragma unroll
      for (int mb = 0; mb < 8; mb++) S[qb][mb] = f32x4{0.f, 0.f, 0.f, 0.f};
    __builtin_amdgcn_s_setprio(1);
    #pragma unroll
    for (int mb = 0; mb < 8; mb++) {
      int r = mb * 16 + l16;
      #pragma unroll
      for (int ku = 0; ku < 4; ku++) {
        s16x8 kf = *(const s16x8*)&Ks[r * 128 + (((ku * 4 + q4) ^ (r & 7)) << 3)];
        S[0][mb] = __builtin_amdgcn_mfma_f32_16x16x32_bf16(kf, qf[0][ku], S[0][mb], 0, 0, 0);
        S[1][mb] = __builtin_amdgcn_mfma_f32_16x16x32_bf16(kf, qf[1][ku], S[1][mb], 0, 0, 0);
      }
    }
    __builtin_amdgcn_s_setprio(0);
    // ---- online softmax (exp2 domain) ----
    s16x8 pf8[2][4];
    #pragma unroll
    for (int qb = 0; qb < 2; qb++) {
      float mx = -1e30f;
      #pragma unroll
      for (int mb = 0; mb < 8; mb++)
        #pragma unroll
        for (int r = 0; r < 4; r++) mx = fmaxf(mx, S[qb][mb][r]);
      mx = fmaxf(mx, __shfl_xor(mx, 16));
      mx = fmaxf(mx, __shfl_xor(mx, 32));
      float mn = fmaxf(m_st[qb], mx);
      float alpha = EXP2F(m_st[qb] - mn);
      m_st[qb] = mn;
      float rs = 0.f;
      #pragma unroll
      for (int mb = 0; mb < 8; mb++)
        #pragma unroll
        for (int r = 0; r < 4; r++) {
          float p = EXP2F(S[qb][mb][r] - mn);
          rs += p;
          pf8[qb][mb >> 1][(mb & 1) * 4 + r] = (short)f2bf(p);
        }
      rs += __shfl_xor(rs, 16);
      rs += __shfl_xor(rs, 32);
      l_st[qb] = l_st[qb] * alpha + rs;
      #pragma unroll
      for (int hb = 0; hb < 8; hb++) O[qb][hb] *= alpha;
    }
    // ---- PV with K=32 MFMA: s-blocks of 32 ----
    __builtin_amdgcn_s_setprio(1);
    #pragma unroll
    for (int su = 0; su < 4; su++) {
      #pragma unroll
      for (int hb = 0; hb < 8; hb++) {
        int r = hb * 16 + l16;
        int c0 = su * 8 + q4;       // s = su*32 + q4*4 .. +3      (regs 0-3)
        int c1 = c0 + 4;            // s = su*32 + 16 + q4*4 .. +3 (regs 4-7)
        s16x4 v0 = *(const s16x4*)&Vs[r * 128 + (((c0 >> 1) ^ (r & 7)) << 3) + ((c0 & 1) << 2)];
        s16x4 v1 = *(const s16x4*)&Vs[r * 128 + (((c1 >> 1) ^ (r & 7)) << 3) + ((c1 & 1) << 2)];
        s16x8 vf = __builtin_shufflevector(v0, v1, 0, 1, 2, 3, 4, 5, 6, 7);
        O[0][hb] = __builtin_amdgcn_mfma_f32_16x16x32_bf16(vf, pf8[0][su], O[0][hb], 0, 0, 0);
        O[1][hb] = __builtin_amdgcn_mfma_f32_16x16x32_bf16(vf, pf8[1][su], O[1][hb], 0, 0, 0);
      }
    }
    __builtin_amdgcn_s_setprio(0);
  }
  #pragma unroll
  for (int qb = 0; qb < 2; qb++) {
    float inv = 1.f / l_st[qb];
    int t = b * TT + qt * 128 + wave * 32 + qb * 16 + l16;
    #pragma unroll
    for (int hb = 0; hb < 8; hb++) {
      ushort4 o;
      o.x = f2bf(O[qb][hb][0] * inv);
      o.y = f2bf(O[qb][hb][1] * inv);
      o.z = f2bf(O[qb][hb][2] * inv);
      o.w = f2bf(O[qb][hb][3] * inv);
      *(ushort4*)&enc[(size_t)t * NHC + n * HD + hb * 16 + q4 * 4] = o;
    }
  }
}

extern "C" void kernel_launch(void* const* d_in, const int* in_sizes, int n_in,
                              void* d_out, int out_size, void* d_ws, size_t ws_size,
                              hipStream_t stream) {
  const float* x  = (const float*)d_in[0];
  const float* Wq = (const float*)d_in[1];
  const float* Wk = (const float*)d_in[2];
  const float* Wv = (const float*)d_in[3];
  const float* Wo = (const float*)d_in[4];
  float* out = (float*)d_out;

  char* ws = (char*)d_ws;
  size_t off = 0;
  auto alloc = [&](size_t bytes) -> void* {
    void* p = ws + off;
    off += (bytes + 255) & ~(size_t)255;
    return p;
  };
  unsigned short* xb    = (unsigned short*)alloc((size_t)BT * CC * 2);
  unsigned short* wqkvt = (unsigned short*)alloc((size_t)QKVC * CC * 2);
  unsigned short* wot   = (unsigned short*)alloc((size_t)CC * NHC * 2);
  unsigned short* qkv   = (unsigned short*)alloc((size_t)BT * QKVC * 2);
  unsigned short* qrb   = (unsigned short*)alloc((size_t)BT * NHC * 2);
  unsigned short* krb   = (unsigned short*)alloc((size_t)BT * KHC * 2);
  unsigned short* vTb   = (unsigned short*)alloc((size_t)BB * KVH * HD * TT * 2);
  unsigned short* encb  = (unsigned short*)alloc((size_t)BT * NHC * 2);
  float* stab = (float*)alloc((size_t)TT * 64 * 4);
  float* ctab = (float*)alloc((size_t)TT * 64 * 4);

  dim3 tb(32, 8);
  cvt_f2b<<<(BT*CC/4 + 255)/256, 256, 0, stream>>>(x, xb, BT*CC/4);
  trans_f2b<<<dim3(NHC/32, CC/32), tb, 0, stream>>>(Wq, wqkvt, CC, NHC);
  trans_f2b<<<dim3(KHC/32, CC/32), tb, 0, stream>>>(Wk, wqkvt + (size_t)NHC*CC, CC, KHC);
  trans_f2b<<<dim3(KHC/32, CC/32), tb, 0, stream>>>(Wv, wqkvt + (size_t)(NHC+KHC)*CC, CC, KHC);
  trans_f2b<<<dim3(NHC/32, NHC/32), tb, 0, stream>>>(Wo, wot, NHC, CC);
  sincos_init<<<(TT*64 + 255)/256, 256, 0, stream>>>(stab, ctab);
  gemm_nt<1><<<dim3(QKVC/128, BT/128), 256, 0, stream>>>(xb, wqkvt, qkv, BT, QKVC, CC);
  postproc<<<BT, 256, 0, stream>>>(qkv, qrb, krb, stab, ctab);
  trans_v<<<dim3(TT/32, HD/32, BB*KVH), tb, 0, stream>>>(qkv, vTb);
  attn<<<BB * NHEAD * (TT/128), 256, 0, stream>>>(qrb, krb, vTb, encb);
  gemm_nt<0><<<dim3(CC/128, BT/128), 256, 0, stream>>>(encb, wot, out, BT, CC, NHC);
}

// Round 2
// 559.819 us; speedup vs baseline: 1.4680x; 1.4680x over previous
//
#include <hip/hip_runtime.h>
#include <hip/hip_bf16.h>
#include <math.h>

typedef __attribute__((ext_vector_type(4))) float f32x4;
typedef __attribute__((ext_vector_type(8))) short s16x8;
typedef __attribute__((ext_vector_type(4))) short s16x4;

#define BB 4
#define TT 2048
#define CC 2048
#define NHEAD 16
#define KVH 4
#define HD 128
#define BT (BB*TT)      // 8192
#define NHC 2048        // N*H
#define KHC 512         // K*H
#define QKVC 3072

__device__ __forceinline__ float bf2f(unsigned short u) {
  union { unsigned u; float f; } v; v.u = ((unsigned)u) << 16; return v.f;
}
__device__ __forceinline__ unsigned short f2bf(float f) {
  union { float f; unsigned u; } v; v.f = f;
  unsigned r = v.u + 0x7fff + ((v.u >> 16) & 1);
  return (unsigned short)(r >> 16);
}

#if defined(__has_builtin)
#if __has_builtin(__builtin_amdgcn_exp2f)
#define EXP2F(x) __builtin_amdgcn_exp2f(x)
#endif
#endif
#ifndef EXP2F
#define EXP2F(x) exp2f(x)
#endif

// ---- async global->LDS 16B (lane i lands at ldsbase + i*16; ldsbase must be wave-uniform) ----
__device__ __forceinline__ void glld16(const void* gsrc, void* ldsbase) {
  __builtin_amdgcn_global_load_lds(
      (const __attribute__((address_space(1))) unsigned int*)gsrc,
      (__attribute__((address_space(3))) unsigned int*)(unsigned int)(unsigned long long)ldsbase,
      16, 0, 0);
}

// ---------------- fp32 -> bf16 elementwise ----------------
__global__ void cvt_f2b(const float* __restrict__ in, unsigned short* __restrict__ out, int n4) {
  int i = blockIdx.x * 256 + threadIdx.x;
  if (i >= n4) return;
  float4 v = ((const float4*)in)[i];
  ushort4 o;
  o.x = f2bf(v.x); o.y = f2bf(v.y); o.z = f2bf(v.z); o.w = f2bf(v.w);
  ((ushort4*)out)[i] = o;
}

// ---------------- fp32 [R][Cc] -> bf16 [Cc][R] transpose ----------------
__global__ void trans_f2b(const float* __restrict__ in, unsigned short* __restrict__ out, int R, int Cc) {
  __shared__ float tile[32][33];
  int c0 = blockIdx.x * 32, r0 = blockIdx.y * 32;
  int tx = threadIdx.x, ty = threadIdx.y;
  #pragma unroll
  for (int k = 0; k < 4; k++)
    tile[ty + 8*k][tx] = in[(size_t)(r0 + ty + 8*k) * Cc + c0 + tx];
  __syncthreads();
  #pragma unroll
  for (int k = 0; k < 4; k++)
    out[(size_t)(c0 + ty + 8*k) * R + r0 + tx] = f2bf(tile[tx][ty + 8*k]);
}

// ---------------- V slice transpose bf16 [s][h] -> [h][s] ----------------
__global__ void trans_v(const unsigned short* __restrict__ qkv, unsigned short* __restrict__ vT) {
  __shared__ unsigned short tile[32][33];
  int slice = blockIdx.z;           // b*4+kh
  int s0 = blockIdx.x * 32, h0 = blockIdx.y * 32;
  int tx = threadIdx.x, ty = threadIdx.y;
  const unsigned short* in = qkv + (size_t)(slice >> 2) * TT * QKVC + (NHC + KHC) + (slice & 3) * HD;
  unsigned short* out = vT + (size_t)slice * HD * TT;
  #pragma unroll
  for (int k = 0; k < 4; k++)
    tile[ty + 8*k][tx] = in[(size_t)(s0 + ty + 8*k) * QKVC + h0 + tx];
  __syncthreads();
  #pragma unroll
  for (int k = 0; k < 4; k++)
    out[(size_t)(h0 + ty + 8*k) * TT + s0 + tx] = tile[tx][ty + 8*k];
}

// ---------------- RoPE sin/cos table (fp64 precision) ----------------
__global__ void sincos_init(float* __restrict__ stab, float* __restrict__ ctab) {
  int idx = blockIdx.x * 256 + threadIdx.x;
  if (idx >= TT * 64) return;
  int t = idx >> 6, i = idx & 63;
  double inv = exp(-log(10000.0) * ((double)i / 64.0));
  double ang = (double)t * inv;
  stab[idx] = (float)sin(ang);
  ctab[idx] = (float)cos(ang);
}

// ---------------- NT GEMM: C[M][Nn] = A[M][Kd] * Bt[Nn][Kd]^T ----------------
// m97-style: global_load_lds dwordx4 staging, 128x128 tile, BK=32, 16 MFMA/wave/iter.
template<int OUTBF16>
__global__ __launch_bounds__(256) void gemm_nt(
    const unsigned short* __restrict__ A, const unsigned short* __restrict__ Bt,
    void* __restrict__ outp, int M, int Nn, int Kd) {
  __shared__ unsigned short As[128 * 32];
  __shared__ unsigned short Bs[128 * 32];
  int tid = threadIdx.x;
  int wave = tid >> 6, lane = tid & 63, q4 = lane >> 4, l16 = lane & 15;
  int m0 = blockIdx.y * 128, n0 = blockIdx.x * 128;
  int wm = (wave & 1) * 64, wn = (wave >> 1) * 64;
  f32x4 acc[4][4];
  #pragma unroll
  for (int i = 0; i < 4; i++)
    #pragma unroll
    for (int j = 0; j < 4; j++) acc[i][j] = f32x4{0.f, 0.f, 0.f, 0.f};

  int r0s = wave * 32 + (lane >> 2);
  int r1s = r0s + 16;
  int cg0 = (lane & 3) ^ ((r0s >> 1) & 3);
  int cg1 = (lane & 3) ^ ((r1s >> 1) & 3);
  const unsigned short* Ag0 = A + (size_t)(m0 + r0s) * Kd + cg0 * 8;
  const unsigned short* Ag1 = A + (size_t)(m0 + r1s) * Kd + cg1 * 8;
  const unsigned short* Bg0 = Bt + (size_t)(n0 + r0s) * Kd + cg0 * 8;
  const unsigned short* Bg1 = Bt + (size_t)(n0 + r1s) * Kd + cg1 * 8;
  unsigned short* lA0 = As + (wave * 2 + 0) * 512;
  unsigned short* lA1 = As + (wave * 2 + 1) * 512;
  unsigned short* lB0 = Bs + (wave * 2 + 0) * 512;
  unsigned short* lB1 = Bs + (wave * 2 + 1) * 512;

  int aoff[4], boff[4];
  #pragma unroll
  for (int f = 0; f < 4; f++) {
    int Ra = wm + f * 16 + l16;
    int Rb = wn + f * 16 + l16;
    aoff[f] = Ra * 32 + (q4 ^ ((Ra >> 1) & 3)) * 8;
    boff[f] = Rb * 32 + (q4 ^ ((Rb >> 1) & 3)) * 8;
  }

  for (int k0 = 0; k0 < Kd; k0 += 32) {
    __syncthreads();
    glld16(Ag0 + k0, lA0);
    glld16(Ag1 + k0, lA1);
    glld16(Bg0 + k0, lB0);
    glld16(Bg1 + k0, lB1);
    asm volatile("s_waitcnt vmcnt(0)" ::: "memory");
    __syncthreads();
    s16x8 af[4], bfr[4];
    #pragma unroll
    for (int mf = 0; mf < 4; mf++) af[mf] = *(const s16x8*)&As[aoff[mf]];
    #pragma unroll
    for (int nf = 0; nf < 4; nf++) bfr[nf] = *(const s16x8*)&Bs[boff[nf]];
    #pragma unroll
    for (int mf = 0; mf < 4; mf++)
      #pragma unroll
      for (int nf = 0; nf < 4; nf++)
        acc[mf][nf] = __builtin_amdgcn_mfma_f32_16x16x32_bf16(af[mf], bfr[nf], acc[mf][nf], 0, 0, 0);
  }
  #pragma unroll
  for (int mf = 0; mf < 4; mf++)
    #pragma unroll
    for (int nf = 0; nf < 4; nf++)
      #pragma unroll
      for (int r = 0; r < 4; r++) {
        int row = m0 + wm + mf*16 + q4*4 + r;
        int col = n0 + wn + nf*16 + l16;
        float v = acc[mf][nf][r];
        if (OUTBF16) ((unsigned short*)outp)[(size_t)row * Nn + col] = f2bf(v);
        else         ((float*)outp)[(size_t)row * Nn + col] = v;
      }
}

// ---------------- RMSNorm + RoPE + scale ----------------
// NOTE: q scale folds in log2(e) so attention can use exp2 directly
// (softmax is exactly invariant: p = exp(S-m) = 2^(S*log2e - m*log2e)).
__global__ __launch_bounds__(256) void postproc(
    const unsigned short* __restrict__ qkv, unsigned short* __restrict__ qr,
    unsigned short* __restrict__ kr, const float* __restrict__ stab, const float* __restrict__ ctab) {
  __shared__ float sh[NHC + KHC];
  __shared__ float redq[4], redk[4];
  int row = blockIdx.x;
  int t = row & (TT - 1);
  int tid = threadIdx.x;
  const unsigned short* base = qkv + (size_t)row * QKVC;
  float sq = 0.f, sk = 0.f;
  uint4 qv = *(const uint4*)&base[tid * 8];
  const unsigned short* qp = (const unsigned short*)&qv;
  #pragma unroll
  for (int i = 0; i < 8; i++) { float f = bf2f(qp[i]); sh[tid*8 + i] = f; sq += f*f; }
  unsigned kv = *(const unsigned*)&base[NHC + tid*2];
  {
    float f0 = bf2f((unsigned short)(kv & 0xffff));
    float f1 = bf2f((unsigned short)(kv >> 16));
    sh[NHC + tid*2] = f0; sh[NHC + tid*2 + 1] = f1;
    sk += f0*f0 + f1*f1;
  }
  #pragma unroll
  for (int off = 32; off > 0; off >>= 1) { sq += __shfl_xor(sq, off); sk += __shfl_xor(sk, off); }
  if ((tid & 63) == 0) { redq[tid >> 6] = sq; redk[tid >> 6] = sk; }
  __syncthreads();
  float fq = rsqrtf((redq[0]+redq[1]+redq[2]+redq[3]) * (1.f/NHC) + 1e-6f)
             * (0.08838834764831845f * 1.4426950408889634f);
  float fk = rsqrtf((redk[0]+redk[1]+redk[2]+redk[3]) * (1.f/KHC) + 1e-6f);
  #pragma unroll
  for (int pi = 0; pi < 4; pi++) {
    int P = pi * 256 + tid;
    int head = P >> 6, i = P & 63;
    float s = stab[t*64 + i], c = ctab[t*64 + i];
    float x1 = sh[head*128 + i], x2 = sh[head*128 + i + 64];
    qr[(size_t)row * NHC + head*128 + i]      = f2bf((x1*c - x2*s) * fq);
    qr[(size_t)row * NHC + head*128 + i + 64] = f2bf((x2*c + x1*s) * fq);
  }
  {
    int head = tid >> 6, i = tid & 63;
    float s = stab[t*64 + i], c = ctab[t*64 + i];
    float x1 = sh[NHC + head*128 + i], x2 = sh[NHC + head*128 + i + 64];
    kr[(size_t)row * KHC + head*128 + i]      = f2bf((x1*c - x2*s) * fk);
    kr[(size_t)row * KHC + head*128 + i + 64] = f2bf((x2*c + x1*s) * fk);
  }
}

// ---------------- flash attention v4 ----------------
// vs v2 (255us baseline):
//  - KV tile 64 rows, DOUBLE-BUFFERED, staged via global_load_lds (zero VGPR
//    cost -> no spill, unlike v3's register prefetch which scratch-spilled).
//    2-phase pipeline: issue stage(j+1) -> compute(j) -> vmcnt(0)+barrier.
//  - Swizzle moved to per-lane GLOBAL source address (glld16 writes linearly);
//    LDS read side keeps the same XOR swizzle (both-sides involution).
//  - PV uses K=32 MFMA (verified in round 1): half the PV instructions.
//  - exp2-domain softmax (log2e folded into q by postproc).
//  - T13 defer-max (THR=8 in exp2 domain): skip O-rescale when max growth small.
//  - T5 setprio around MFMA clusters.
__global__ __launch_bounds__(256, 2) void attn(
    const unsigned short* __restrict__ qr, const unsigned short* __restrict__ kr,
    const unsigned short* __restrict__ vT, unsigned short* __restrict__ enc) {
  __shared__ unsigned short Ks[2][64 * 128];   // 16KB each; Ks[0]+Ks[1] holds Q in prologue
  __shared__ unsigned short Vs[2][128 * 64];   // 16KB each, layout [h][s-chunk]
  int tid = threadIdx.x;
  int wave = tid >> 6, lane = tid & 63, q4 = lane >> 4, l16 = lane & 15;
  int bid = blockIdx.x;
  int qt = bid & 15, n = (bid >> 4) & 15, b = bid >> 8, kh = n >> 2;

  const unsigned short* kbase = kr + ((size_t)(b * TT)) * KHC + kh * HD;
  const unsigned short* vbase = vT + ((size_t)((b * KVH + kh) * HD)) * TT;

  // --- stage K tile j (64 rows x 128 cols) into Ks[kb]; source pre-swizzled ---
  auto stageK = [&](int j, int kb) {
    const unsigned short* base = kbase + (size_t)(j * 64) * KHC;
    #pragma unroll
    for (int t = 0; t < 4; t++) {
      int L = wave * 4 + t;              // 1KB chunk index, 4 rows each
      int r = L * 4 + (lane >> 4);
      int cg = (lane & 15) ^ (r & 7);
      glld16(base + (size_t)r * KHC + cg * 8, &Ks[kb][L * 512]);
    }
  };
  // --- stage V tile j (128 h-rows x 64 s-cols) into Vs[vb] ---
  auto stageV = [&](int j, int vb) {
    const unsigned short* base = vbase + j * 64;
    #pragma unroll
    for (int t = 0; t < 4; t++) {
      int L = wave * 4 + t;              // 1KB chunk index, 8 rows each
      int r = L * 8 + (lane >> 3);
      int cg = (lane & 7) ^ (r & 7);
      glld16(base + (size_t)r * TT + cg * 8, &Vs[vb][L * 512]);
    }
  };

  // --- prologue: Q -> Ks[0..1] (32KB) + V0 -> Vs[0], then qf regs, then K0 ---
  {
    const unsigned short* base = qr + ((size_t)(b * TT + qt * 128)) * NHC + n * HD;
    #pragma unroll
    for (int t = 0; t < 8; t++) {
      int L = wave * 8 + t;
      int r = L * 4 + (lane >> 4);
      int cg = (lane & 15) ^ (r & 7);
      glld16(base + (size_t)r * NHC + cg * 8, (unsigned short*)Ks + L * 512);
    }
  }
  stageV(0, 0);
  asm volatile("s_waitcnt vmcnt(0)" ::: "memory");
  __syncthreads();
  s16x8 qf[2][4];
  #pragma unroll
  for (int qb = 0; qb < 2; qb++)
    #pragma unroll
    for (int ku = 0; ku < 4; ku++) {
      int r = wave * 32 + qb * 16 + l16;
      qf[qb][ku] = *(const s16x8*)&((const unsigned short*)Ks)[r * 128 + (((ku * 4 + q4) ^ (r & 7)) << 3)];
    }
  __syncthreads();           // all waves done reading Q before K0 overwrites Ks[0]
  stageK(0, 0);
  asm volatile("s_waitcnt vmcnt(0)" ::: "memory");
  __syncthreads();

  float m_st[2] = {-1e30f, -1e30f}, l_st[2] = {0.f, 0.f};
  f32x4 O[2][8];
  #pragma unroll
  for (int qb = 0; qb < 2; qb++)
    #pragma unroll
    for (int hb = 0; hb < 8; hb++) O[qb][hb] = f32x4{0.f, 0.f, 0.f, 0.f};

  for (int j = 0; j < 32; j++) {
    int cur = j & 1;
    // issue next-tile loads; latency hides under this tile's compute
    if (j < 31) { stageK(j + 1, cur ^ 1); stageV(j + 1, cur ^ 1); }
    // ---- QK^T (S^T layout): 64 k-rows ----
    f32x4 S[2][4];
    #pragma unroll
    for (int qb = 0; qb < 2; qb++)
      #pragma unroll
      for (int mb = 0; mb < 4; mb++) S[qb][mb] = f32x4{0.f, 0.f, 0.f, 0.f};
    __builtin_amdgcn_s_setprio(1);
    #pragma unroll
    for (int mb = 0; mb < 4; mb++) {
      int r = mb * 16 + l16;
      #pragma unroll
      for (int ku = 0; ku < 4; ku++) {
        s16x8 kf = *(const s16x8*)&Ks[cur][r * 128 + (((ku * 4 + q4) ^ (r & 7)) << 3)];
        S[0][mb] = __builtin_amdgcn_mfma_f32_16x16x32_bf16(kf, qf[0][ku], S[0][mb], 0, 0, 0);
        S[1][mb] = __builtin_amdgcn_mfma_f32_16x16x32_bf16(kf, qf[1][ku], S[1][mb], 0, 0, 0);
      }
    }
    __builtin_amdgcn_s_setprio(0);
    // ---- online softmax (exp2 domain, defer-max THR=8) ----
    s16x8 pf8[2][2];
    #pragma unroll
    for (int qb = 0; qb < 2; qb++) {
      float mx = -1e30f;
      #pragma unroll
      for (int mb = 0; mb < 4; mb++)
        #pragma unroll
        for (int r = 0; r < 4; r++) mx = fmaxf(mx, S[qb][mb][r]);
      mx = fmaxf(mx, __shfl_xor(mx, 16));
      mx = fmaxf(mx, __shfl_xor(mx, 32));
      if (!__all(mx - m_st[qb] <= 8.f)) {
        float alpha = EXP2F(m_st[qb] - mx);
        m_st[qb] = mx;
        l_st[qb] *= alpha;
        #pragma unroll
        for (int hb = 0; hb < 8; hb++) O[qb][hb] *= alpha;
      }
      float mcur = m_st[qb];
      float rs = 0.f;
      #pragma unroll
      for (int mb = 0; mb < 4; mb++)
        #pragma unroll
        for (int r = 0; r < 4; r++) {
          float p = EXP2F(S[qb][mb][r] - mcur);
          rs += p;
          pf8[qb][mb >> 1][(mb & 1) * 4 + r] = (short)f2bf(p);
        }
      rs += __shfl_xor(rs, 16);
      rs += __shfl_xor(rs, 32);
      l_st[qb] += rs;
    }
    // ---- PV with K=32 MFMA: two s-blocks of 32 ----
    __builtin_amdgcn_s_setprio(1);
    #pragma unroll
    for (int su = 0; su < 2; su++) {
      #pragma unroll
      for (int hb = 0; hb < 8; hb++) {
        int r = hb * 16 + l16;
        int c0 = su * 8 + q4;       // s = su*32 + q4*4 .. +3      (regs 0-3)
        int c1 = c0 + 4;            // s = su*32 + 16 + q4*4 .. +3 (regs 4-7)
        s16x4 v0 = *(const s16x4*)&Vs[cur][r * 64 + (((c0 >> 1) ^ (r & 7)) << 3) + ((c0 & 1) << 2)];
        s16x4 v1 = *(const s16x4*)&Vs[cur][r * 64 + (((c1 >> 1) ^ (r & 7)) << 3) + ((c1 & 1) << 2)];
        s16x8 vf = __builtin_shufflevector(v0, v1, 0, 1, 2, 3, 4, 5, 6, 7);
        O[0][hb] = __builtin_amdgcn_mfma_f32_16x16x32_bf16(vf, pf8[0][su], O[0][hb], 0, 0, 0);
        O[1][hb] = __builtin_amdgcn_mfma_f32_16x16x32_bf16(vf, pf8[1][su], O[1][hb], 0, 0, 0);
      }
    }
    __builtin_amdgcn_s_setprio(0);
    // next tile's loads must have landed; one barrier per iteration
    asm volatile("s_waitcnt vmcnt(0)" ::: "memory");
    __syncthreads();
  }
  #pragma unroll
  for (int qb = 0; qb < 2; qb++) {
    float inv = 1.f / l_st[qb];
    int t = b * TT + qt * 128 + wave * 32 + qb * 16 + l16;
    #pragma unroll
    for (int hb = 0; hb < 8; hb++) {
      ushort4 o;
      o.x = f2bf(O[qb][hb][0] * inv);
      o.y = f2bf(O[qb][hb][1] * inv);
      o.z = f2bf(O[qb][hb][2] * inv);
      o.w = f2bf(O[qb][hb][3] * inv);
      *(ushort4*)&enc[(size_t)t * NHC + n * HD + hb * 16 + q4 * 4] = o;
    }
  }
}

extern "C" void kernel_launch(void* const* d_in, const int* in_sizes, int n_in,
                              void* d_out, int out_size, void* d_ws, size_t ws_size,
                              hipStream_t stream) {
  const float* x  = (const float*)d_in[0];
  const float* Wq = (const float*)d_in[1];
  const float* Wk = (const float*)d_in[2];
  const float* Wv = (const float*)d_in[3];
  const float* Wo = (const float*)d_in[4];
  float* out = (float*)d_out;

  char* ws = (char*)d_ws;
  size_t off = 0;
  auto alloc = [&](size_t bytes) -> void* {
    void* p = ws + off;
    off += (bytes + 255) & ~(size_t)255;
    return p;
  };
  unsigned short* xb    = (unsigned short*)alloc((size_t)BT * CC * 2);
  unsigned short* wqkvt = (unsigned short*)alloc((size_t)QKVC * CC * 2);
  unsigned short* wot   = (unsigned short*)alloc((size_t)CC * NHC * 2);
  unsigned short* qkv   = (unsigned short*)alloc((size_t)BT * QKVC * 2);
  unsigned short* qrb   = (unsigned short*)alloc((size_t)BT * NHC * 2);
  unsigned short* krb   = (unsigned short*)alloc((size_t)BT * KHC * 2);
  unsigned short* vTb   = (unsigned short*)alloc((size_t)BB * KVH * HD * TT * 2);
  unsigned short* encb  = (unsigned short*)alloc((size_t)BT * NHC * 2);
  float* stab = (float*)alloc((size_t)TT * 64 * 4);
  float* ctab = (float*)alloc((size_t)TT * 64 * 4);

  dim3 tb(32, 8);
  cvt_f2b<<<(BT*CC/4 + 255)/256, 256, 0, stream>>>(x, xb, BT*CC/4);
  trans_f2b<<<dim3(NHC/32, CC/32), tb, 0, stream>>>(Wq, wqkvt, CC, NHC);
  trans_f2b<<<dim3(KHC/32, CC/32), tb, 0, stream>>>(Wk, wqkvt + (size_t)NHC*CC, CC, KHC);
  trans_f2b<<<dim3(KHC/32, CC/32), tb, 0, stream>>>(Wv, wqkvt + (size_t)(NHC+KHC)*CC, CC, KHC);
  trans_f2b<<<dim3(NHC/32, NHC/32), tb, 0, stream>>>(Wo, wot, NHC, CC);
  sincos_init<<<(TT*64 + 255)/256, 256, 0, stream>>>(stab, ctab);
  gemm_nt<1><<<dim3(QKVC/128, BT/128), 256, 0, stream>>>(xb, wqkvt, qkv, BT, QKVC, CC);
  postproc<<<BT, 256, 0, stream>>>(qkv, qrb, krb, stab, ctab);
  trans_v<<<dim3(TT/32, HD/32, BB*KVH), tb, 0, stream>>>(qkv, vTb);
  attn<<<BB * NHEAD * (TT/128), 256, 0, stream>>>(qrb, krb, vTb, encb);
  gemm_nt<0><<<dim3(CC/128, BT/128), 256, 0, stream>>>(encb, wot, out, BT, CC, NHC);
}

// Round 3
// 525.408 us; speedup vs baseline: 1.5642x; 1.0655x over previous
//
#include <hip/hip_runtime.h>
#include <hip/hip_bf16.h>
#include <math.h>

typedef __attribute__((ext_vector_type(4))) float f32x4;
typedef __attribute__((ext_vector_type(8))) short s16x8;
typedef __attribute__((ext_vector_type(4))) short s16x4;

#define BB 4
#define TT 2048
#define CC 2048
#define NHEAD 16
#define KVH 4
#define HD 128
#define BT (BB*TT)      // 8192
#define NHC 2048        // N*H
#define KHC 512         // K*H
#define QKVC 3072

__device__ __forceinline__ float bf2f(unsigned short u) {
  union { unsigned u; float f; } v; v.u = ((unsigned)u) << 16; return v.f;
}
__device__ __forceinline__ unsigned short f2bf(float f) {
  union { float f; unsigned u; } v; v.f = f;
  unsigned r = v.u + 0x7fff + ((v.u >> 16) & 1);
  return (unsigned short)(r >> 16);
}

#if defined(__has_builtin)
#if __has_builtin(__builtin_amdgcn_exp2f)
#define EXP2F(x) __builtin_amdgcn_exp2f(x)
#endif
#endif
#ifndef EXP2F
#define EXP2F(x) exp2f(x)
#endif

// ---- async global->LDS 16B (lane i lands at ldsbase + i*16; ldsbase must be wave-uniform) ----
__device__ __forceinline__ void glld16(const void* gsrc, void* ldsbase) {
  __builtin_amdgcn_global_load_lds(
      (const __attribute__((address_space(1))) unsigned int*)gsrc,
      (__attribute__((address_space(3))) unsigned int*)(unsigned int)(unsigned long long)ldsbase,
      16, 0, 0);
}

// ---------------- fp32 -> bf16 elementwise ----------------
__global__ void cvt_f2b(const float* __restrict__ in, unsigned short* __restrict__ out, int n4) {
  int i = blockIdx.x * 256 + threadIdx.x;
  if (i >= n4) return;
  float4 v = ((const float4*)in)[i];
  ushort4 o;
  o.x = f2bf(v.x); o.y = f2bf(v.y); o.z = f2bf(v.z); o.w = f2bf(v.w);
  ((ushort4*)out)[i] = o;
}

// ---------------- fp32 [R][Cc] -> bf16 [Cc][R] transpose ----------------
__global__ void trans_f2b(const float* __restrict__ in, unsigned short* __restrict__ out, int R, int Cc) {
  __shared__ float tile[32][33];
  int c0 = blockIdx.x * 32, r0 = blockIdx.y * 32;
  int tx = threadIdx.x, ty = threadIdx.y;
  #pragma unroll
  for (int k = 0; k < 4; k++)
    tile[ty + 8*k][tx] = in[(size_t)(r0 + ty + 8*k) * Cc + c0 + tx];
  __syncthreads();
  #pragma unroll
  for (int k = 0; k < 4; k++)
    out[(size_t)(c0 + ty + 8*k) * R + r0 + tx] = f2bf(tile[tx][ty + 8*k]);
}

// ---------------- V slice transpose bf16 [s][h] -> [h][s] ----------------
__global__ void trans_v(const unsigned short* __restrict__ qkv, unsigned short* __restrict__ vT) {
  __shared__ unsigned short tile[32][33];
  int slice = blockIdx.z;           // b*4+kh
  int s0 = blockIdx.x * 32, h0 = blockIdx.y * 32;
  int tx = threadIdx.x, ty = threadIdx.y;
  const unsigned short* in = qkv + (size_t)(slice >> 2) * TT * QKVC + (NHC + KHC) + (slice & 3) * HD;
  unsigned short* out = vT + (size_t)slice * HD * TT;
  #pragma unroll
  for (int k = 0; k < 4; k++)
    tile[ty + 8*k][tx] = in[(size_t)(s0 + ty + 8*k) * QKVC + h0 + tx];
  __syncthreads();
  #pragma unroll
  for (int k = 0; k < 4; k++)
    out[(size_t)(h0 + ty + 8*k) * TT + s0 + tx] = tile[tx][ty + 8*k];
}

// ---------------- RoPE sin/cos table (fp64 precision) ----------------
__global__ void sincos_init(float* __restrict__ stab, float* __restrict__ ctab) {
  int idx = blockIdx.x * 256 + threadIdx.x;
  if (idx >= TT * 64) return;
  int t = idx >> 6, i = idx & 63;
  double inv = exp(-log(10000.0) * ((double)i / 64.0));
  double ang = (double)t * inv;
  stab[idx] = (float)sin(ang);
  ctab[idx] = (float)cos(ang);
}

// ---------------- NT GEMM 256x256 tile, BK=64, 8 waves, 2-phase pipeline ----------------
// T3 minimum recipe: issue stage(kt+1 -> buf^1) BEFORE compute(kt), single
// __syncthreads per K-tile (its implicit vmcnt(0) drain == "prefetch landed").
// T2: chunk ^= (row&7) swizzle applied on BOTH glld16 source and ds_read side.
// T1: XCD-aware flat block swizzle (nwg % 8 == 0 for both our shapes).
// Fragment/output mapping identical to the previously verified 128^2 kernel.
template<int OUTBF16>
__global__ __launch_bounds__(512, 2) void gemm256(
    const unsigned short* __restrict__ A, const unsigned short* __restrict__ Bt,
    void* __restrict__ outp, int M, int Nn, int Kd) {
  __shared__ unsigned short As[2][256 * 64];   // 32 KiB per buf
  __shared__ unsigned short Bs[2][256 * 64];
  int tid = threadIdx.x;
  int wave = tid >> 6, lane = tid & 63, q4 = lane >> 4, l16 = lane & 15;

  int gx = Nn >> 8;
  int nwg = gridDim.x;
  int bid = blockIdx.x;
  int bid2 = (nwg & 7) ? bid : ((bid & 7) * (nwg >> 3) + (bid >> 3));
  int bx = bid2 % gx, by = bid2 / gx;
  int m0 = by * 256, n0 = bx * 256;

  int wm = (wave >> 2) * 128;      // 2 M-waves
  int wn = (wave & 3) * 64;        // 4 N-waves

  f32x4 acc[8][4];
  #pragma unroll
  for (int i = 0; i < 8; i++)
    #pragma unroll
    for (int j = 0; j < 4; j++) acc[i][j] = f32x4{0.f, 0.f, 0.f, 0.f};

  const unsigned short* Abase = A + (size_t)m0 * Kd;
  const unsigned short* Bbase = Bt + (size_t)n0 * Kd;

  // staging: 256 rows x 64 K (32 KiB) per matrix = 32 wave-instrs; 4 per wave.
  // linear LDS chunk cf = (wave*4+t)*64 + lane; row = cf>>3, slot = cf&7,
  // global K-chunk = slot ^ (row&7)  (pre-swizzled source; glld writes linear).
  auto stage = [&](const unsigned short* Ak, const unsigned short* Bk, int buf) {
    #pragma unroll
    for (int t = 0; t < 4; t++) {
      int cf = (wave * 4 + t) * 64 + lane;
      int r = cf >> 3, cg = (cf & 7) ^ (r & 7);
      glld16(Ak + (size_t)r * Kd + cg * 8, &As[buf][(wave * 4 + t) * 512]);
    }
    #pragma unroll
    for (int t = 0; t < 4; t++) {
      int cf = (wave * 4 + t) * 64 + lane;
      int r = cf >> 3, cg = (cf & 7) ^ (r & 7);
      glld16(Bk + (size_t)r * Kd + cg * 8, &Bs[buf][(wave * 4 + t) * 512]);
    }
  };

  stage(Abase, Bbase, 0);
  __syncthreads();

  int nkt = Kd >> 6;
  for (int kt = 0; kt < nkt; kt++) {
    int cur = kt & 1;
    if (kt + 1 < nkt) stage(Abase + (kt + 1) * 64, Bbase + (kt + 1) * 64, cur ^ 1);
    #pragma unroll
    for (int ks = 0; ks < 2; ks++) {
      s16x8 af[8], bfv[4];
      int c = ks * 4 + q4;
      #pragma unroll
      for (int mf = 0; mf < 8; mf++) {
        int r = wm + mf * 16 + l16;
        af[mf] = *(const s16x8*)&As[cur][r * 64 + ((c ^ (r & 7)) << 3)];
      }
      #pragma unroll
      for (int nf = 0; nf < 4; nf++) {
        int r = wn + nf * 16 + l16;
        bfv[nf] = *(const s16x8*)&Bs[cur][r * 64 + ((c ^ (r & 7)) << 3)];
      }
      __builtin_amdgcn_s_setprio(1);
      #pragma unroll
      for (int mf = 0; mf < 8; mf++)
        #pragma unroll
        for (int nf = 0; nf < 4; nf++)
          acc[mf][nf] = __builtin_amdgcn_mfma_f32_16x16x32_bf16(af[mf], bfv[nf], acc[mf][nf], 0, 0, 0);
      __builtin_amdgcn_s_setprio(0);
    }
    __syncthreads();   // implicit vmcnt(0): prefetch landed; all reads of cur done
  }

  #pragma unroll
  for (int mf = 0; mf < 8; mf++)
    #pragma unroll
    for (int nf = 0; nf < 4; nf++)
      #pragma unroll
      for (int r = 0; r < 4; r++) {
        int row = m0 + wm + mf * 16 + q4 * 4 + r;
        int col = n0 + wn + nf * 16 + l16;
        float v = acc[mf][nf][r];
        if (OUTBF16) ((unsigned short*)outp)[(size_t)row * Nn + col] = f2bf(v);
        else         ((float*)outp)[(size_t)row * Nn + col] = v;
      }
}

// ---------------- RMSNorm + RoPE + scale ----------------
// NOTE: q scale folds in log2(e) so attention can use exp2 directly
// (softmax is exactly invariant: p = exp(S-m) = 2^(S*log2e - m*log2e)).
__global__ __launch_bounds__(256) void postproc(
    const unsigned short* __restrict__ qkv, unsigned short* __restrict__ qr,
    unsigned short* __restrict__ kr, const float* __restrict__ stab, const float* __restrict__ ctab) {
  __shared__ float sh[NHC + KHC];
  __shared__ float redq[4], redk[4];
  int row = blockIdx.x;
  int t = row & (TT - 1);
  int tid = threadIdx.x;
  const unsigned short* base = qkv + (size_t)row * QKVC;
  float sq = 0.f, sk = 0.f;
  uint4 qv = *(const uint4*)&base[tid * 8];
  const unsigned short* qp = (const unsigned short*)&qv;
  #pragma unroll
  for (int i = 0; i < 8; i++) { float f = bf2f(qp[i]); sh[tid*8 + i] = f; sq += f*f; }
  unsigned kv = *(const unsigned*)&base[NHC + tid*2];
  {
    float f0 = bf2f((unsigned short)(kv & 0xffff));
    float f1 = bf2f((unsigned short)(kv >> 16));
    sh[NHC + tid*2] = f0; sh[NHC + tid*2 + 1] = f1;
    sk += f0*f0 + f1*f1;
  }
  #pragma unroll
  for (int off = 32; off > 0; off >>= 1) { sq += __shfl_xor(sq, off); sk += __shfl_xor(sk, off); }
  if ((tid & 63) == 0) { redq[tid >> 6] = sq; redk[tid >> 6] = sk; }
  __syncthreads();
  float fq = rsqrtf((redq[0]+redq[1]+redq[2]+redq[3]) * (1.f/NHC) + 1e-6f)
             * (0.08838834764831845f * 1.4426950408889634f);
  float fk = rsqrtf((redk[0]+redk[1]+redk[2]+redk[3]) * (1.f/KHC) + 1e-6f);
  #pragma unroll
  for (int pi = 0; pi < 4; pi++) {
    int P = pi * 256 + tid;
    int head = P >> 6, i = P & 63;
    float s = stab[t*64 + i], c = ctab[t*64 + i];
    float x1 = sh[head*128 + i], x2 = sh[head*128 + i + 64];
    qr[(size_t)row * NHC + head*128 + i]      = f2bf((x1*c - x2*s) * fq);
    qr[(size_t)row * NHC + head*128 + i + 64] = f2bf((x2*c + x1*s) * fq);
  }
  {
    int head = tid >> 6, i = tid & 63;
    float s = stab[t*64 + i], c = ctab[t*64 + i];
    float x1 = sh[NHC + head*128 + i], x2 = sh[NHC + head*128 + i + 64];
    kr[(size_t)row * KHC + head*128 + i]      = f2bf((x1*c - x2*s) * fk);
    kr[(size_t)row * KHC + head*128 + i + 64] = f2bf((x2*c + x1*s) * fk);
  }
}

// ---------------- flash attention v4 (unchanged from round 2; 198us verified) ----------------
__global__ __launch_bounds__(256, 2) void attn(
    const unsigned short* __restrict__ qr, const unsigned short* __restrict__ kr,
    const unsigned short* __restrict__ vT, unsigned short* __restrict__ enc) {
  __shared__ unsigned short Ks[2][64 * 128];   // 16KB each; Ks[0]+Ks[1] holds Q in prologue
  __shared__ unsigned short Vs[2][128 * 64];   // 16KB each, layout [h][s-chunk]
  int tid = threadIdx.x;
  int wave = tid >> 6, lane = tid & 63, q4 = lane >> 4, l16 = lane & 15;
  int bid = blockIdx.x;
  int qt = bid & 15, n = (bid >> 4) & 15, b = bid >> 8, kh = n >> 2;

  const unsigned short* kbase = kr + ((size_t)(b * TT)) * KHC + kh * HD;
  const unsigned short* vbase = vT + ((size_t)((b * KVH + kh) * HD)) * TT;

  auto stageK = [&](int j, int kb) {
    const unsigned short* base = kbase + (size_t)(j * 64) * KHC;
    #pragma unroll
    for (int t = 0; t < 4; t++) {
      int L = wave * 4 + t;
      int r = L * 4 + (lane >> 4);
      int cg = (lane & 15) ^ (r & 7);
      glld16(base + (size_t)r * KHC + cg * 8, &Ks[kb][L * 512]);
    }
  };
  auto stageV = [&](int j, int vb) {
    const unsigned short* base = vbase + j * 64;
    #pragma unroll
    for (int t = 0; t < 4; t++) {
      int L = wave * 4 + t;
      int r = L * 8 + (lane >> 3);
      int cg = (lane & 7) ^ (r & 7);
      glld16(base + (size_t)r * TT + cg * 8, &Vs[vb][L * 512]);
    }
  };

  {
    const unsigned short* base = qr + ((size_t)(b * TT + qt * 128)) * NHC + n * HD;
    #pragma unroll
    for (int t = 0; t < 8; t++) {
      int L = wave * 8 + t;
      int r = L * 4 + (lane >> 4);
      int cg = (lane & 15) ^ (r & 7);
      glld16(base + (size_t)r * NHC + cg * 8, (unsigned short*)Ks + L * 512);
    }
  }
  stageV(0, 0);
  asm volatile("s_waitcnt vmcnt(0)" ::: "memory");
  __syncthreads();
  s16x8 qf[2][4];
  #pragma unroll
  for (int qb = 0; qb < 2; qb++)
    #pragma unroll
    for (int ku = 0; ku < 4; ku++) {
      int r = wave * 32 + qb * 16 + l16;
      qf[qb][ku] = *(const s16x8*)&((const unsigned short*)Ks)[r * 128 + (((ku * 4 + q4) ^ (r & 7)) << 3)];
    }
  __syncthreads();
  stageK(0, 0);
  asm volatile("s_waitcnt vmcnt(0)" ::: "memory");
  __syncthreads();

  float m_st[2] = {-1e30f, -1e30f}, l_st[2] = {0.f, 0.f};
  f32x4 O[2][8];
  #pragma unroll
  for (int qb = 0; qb < 2; qb++)
    #pragma unroll
    for (int hb = 0; hb < 8; hb++) O[qb][hb] = f32x4{0.f, 0.f, 0.f, 0.f};

  for (int j = 0; j < 32; j++) {
    int cur = j & 1;
    if (j < 31) { stageK(j + 1, cur ^ 1); stageV(j + 1, cur ^ 1); }
    f32x4 S[2][4];
    #pragma unroll
    for (int qb = 0; qb < 2; qb++)
      #pragma unroll
      for (int mb = 0; mb < 4; mb++) S[qb][mb] = f32x4{0.f, 0.f, 0.f, 0.f};
    __builtin_amdgcn_s_setprio(1);
    #pragma unroll
    for (int mb = 0; mb < 4; mb++) {
      int r = mb * 16 + l16;
      #pragma unroll
      for (int ku = 0; ku < 4; ku++) {
        s16x8 kf = *(const s16x8*)&Ks[cur][r * 128 + (((ku * 4 + q4) ^ (r & 7)) << 3)];
        S[0][mb] = __builtin_amdgcn_mfma_f32_16x16x32_bf16(kf, qf[0][ku], S[0][mb], 0, 0, 0);
        S[1][mb] = __builtin_amdgcn_mfma_f32_16x16x32_bf16(kf, qf[1][ku], S[1][mb], 0, 0, 0);
      }
    }
    __builtin_amdgcn_s_setprio(0);
    s16x8 pf8[2][2];
    #pragma unroll
    for (int qb = 0; qb < 2; qb++) {
      float mx = -1e30f;
      #pragma unroll
      for (int mb = 0; mb < 4; mb++)
        #pragma unroll
        for (int r = 0; r < 4; r++) mx = fmaxf(mx, S[qb][mb][r]);
      mx = fmaxf(mx, __shfl_xor(mx, 16));
      mx = fmaxf(mx, __shfl_xor(mx, 32));
      if (!__all(mx - m_st[qb] <= 8.f)) {
        float alpha = EXP2F(m_st[qb] - mx);
        m_st[qb] = mx;
        l_st[qb] *= alpha;
        #pragma unroll
        for (int hb = 0; hb < 8; hb++) O[qb][hb] *= alpha;
      }
      float mcur = m_st[qb];
      float rs = 0.f;
      #pragma unroll
      for (int mb = 0; mb < 4; mb++)
        #pragma unroll
        for (int r = 0; r < 4; r++) {
          float p = EXP2F(S[qb][mb][r] - mcur);
          rs += p;
          pf8[qb][mb >> 1][(mb & 1) * 4 + r] = (short)f2bf(p);
        }
      rs += __shfl_xor(rs, 16);
      rs += __shfl_xor(rs, 32);
      l_st[qb] += rs;
    }
    __builtin_amdgcn_s_setprio(1);
    #pragma unroll
    for (int su = 0; su < 2; su++) {
      #pragma unroll
      for (int hb = 0; hb < 8; hb++) {
        int r = hb * 16 + l16;
        int c0 = su * 8 + q4;
        int c1 = c0 + 4;
        s16x4 v0 = *(const s16x4*)&Vs[cur][r * 64 + (((c0 >> 1) ^ (r & 7)) << 3) + ((c0 & 1) << 2)];
        s16x4 v1 = *(const s16x4*)&Vs[cur][r * 64 + (((c1 >> 1) ^ (r & 7)) << 3) + ((c1 & 1) << 2)];
        s16x8 vf = __builtin_shufflevector(v0, v1, 0, 1, 2, 3, 4, 5, 6, 7);
        O[0][hb] = __builtin_amdgcn_mfma_f32_16x16x32_bf16(vf, pf8[0][su], O[0][hb], 0, 0, 0);
        O[1][hb] = __builtin_amdgcn_mfma_f32_16x16x32_bf16(vf, pf8[1][su], O[1][hb], 0, 0, 0);
      }
    }
    __builtin_amdgcn_s_setprio(0);
    asm volatile("s_waitcnt vmcnt(0)" ::: "memory");
    __syncthreads();
  }
  #pragma unroll
  for (int qb = 0; qb < 2; qb++) {
    float inv = 1.f / l_st[qb];
    int t = b * TT + qt * 128 + wave * 32 + qb * 16 + l16;
    #pragma unroll
    for (int hb = 0; hb < 8; hb++) {
      ushort4 o;
      o.x = f2bf(O[qb][hb][0] * inv);
      o.y = f2bf(O[qb][hb][1] * inv);
      o.z = f2bf(O[qb][hb][2] * inv);
      o.w = f2bf(O[qb][hb][3] * inv);
      *(ushort4*)&enc[(size_t)t * NHC + n * HD + hb * 16 + q4 * 4] = o;
    }
  }
}

extern "C" void kernel_launch(void* const* d_in, const int* in_sizes, int n_in,
                              void* d_out, int out_size, void* d_ws, size_t ws_size,
                              hipStream_t stream) {
  const float* x  = (const float*)d_in[0];
  const float* Wq = (const float*)d_in[1];
  const float* Wk = (const float*)d_in[2];
  const float* Wv = (const float*)d_in[3];
  const float* Wo = (const float*)d_in[4];
  float* out = (float*)d_out;

  char* ws = (char*)d_ws;
  size_t off = 0;
  auto alloc = [&](size_t bytes) -> void* {
    void* p = ws + off;
    off += (bytes + 255) & ~(size_t)255;
    return p;
  };
  unsigned short* xb    = (unsigned short*)alloc((size_t)BT * CC * 2);
  unsigned short* wqkvt = (unsigned short*)alloc((size_t)QKVC * CC * 2);
  unsigned short* wot   = (unsigned short*)alloc((size_t)CC * NHC * 2);
  unsigned short* qkv   = (unsigned short*)alloc((size_t)BT * QKVC * 2);
  unsigned short* qrb   = (unsigned short*)alloc((size_t)BT * NHC * 2);
  unsigned short* krb   = (unsigned short*)alloc((size_t)BT * KHC * 2);
  unsigned short* vTb   = (unsigned short*)alloc((size_t)BB * KVH * HD * TT * 2);
  unsigned short* encb  = (unsigned short*)alloc((size_t)BT * NHC * 2);
  float* stab = (float*)alloc((size_t)TT * 64 * 4);
  float* ctab = (float*)alloc((size_t)TT * 64 * 4);

  dim3 tb(32, 8);
  cvt_f2b<<<(BT*CC/4 + 255)/256, 256, 0, stream>>>(x, xb, BT*CC/4);
  trans_f2b<<<dim3(NHC/32, CC/32), tb, 0, stream>>>(Wq, wqkvt, CC, NHC);
  trans_f2b<<<dim3(KHC/32, CC/32), tb, 0, stream>>>(Wk, wqkvt + (size_t)NHC*CC, CC, KHC);
  trans_f2b<<<dim3(KHC/32, CC/32), tb, 0, stream>>>(Wv, wqkvt + (size_t)(NHC+KHC)*CC, CC, KHC);
  trans_f2b<<<dim3(NHC/32, NHC/32), tb, 0, stream>>>(Wo, wot, NHC, CC);
  sincos_init<<<(TT*64 + 255)/256, 256, 0, stream>>>(stab, ctab);
  gemm256<1><<<(BT/256) * (QKVC/256), 512, 0, stream>>>(xb, wqkvt, qkv, BT, QKVC, CC);
  postproc<<<BT, 256, 0, stream>>>(qkv, qrb, krb, stab, ctab);
  trans_v<<<dim3(TT/32, HD/32, BB*KVH), tb, 0, stream>>>(qkv, vTb);
  attn<<<BB * NHEAD * (TT/128), 256, 0, stream>>>(qrb, krb, vTb, encb);
  gemm256<0><<<(BT/256) * (CC/256), 512, 0, stream>>>(encb, wot, out, BT, CC, NHC);
}

// Round 4
// 521.624 us; speedup vs baseline: 1.5755x; 1.0073x over previous
//
#include <hip/hip_runtime.h>
#include <hip/hip_bf16.h>
#include <math.h>

typedef __attribute__((ext_vector_type(4))) float f32x4;
typedef __attribute__((ext_vector_type(8))) short s16x8;
typedef __attribute__((ext_vector_type(4))) short s16x4;

#define BB 4
#define TT 2048
#define CC 2048
#define NHEAD 16
#define KVH 4
#define HD 128
#define BT (BB*TT)      // 8192
#define NHC 2048        // N*H
#define KHC 512         // K*H
#define QKVC 3072

__device__ __forceinline__ float bf2f(unsigned short u) {
  union { unsigned u; float f; } v; v.u = ((unsigned)u) << 16; return v.f;
}
__device__ __forceinline__ unsigned short f2bf(float f) {
  union { float f; unsigned u; } v; v.f = f;
  unsigned r = v.u + 0x7fff + ((v.u >> 16) & 1);
  return (unsigned short)(r >> 16);
}

#if defined(__has_builtin)
#if __has_builtin(__builtin_amdgcn_exp2f)
#define EXP2F(x) __builtin_amdgcn_exp2f(x)
#endif
#endif
#ifndef EXP2F
#define EXP2F(x) exp2f(x)
#endif

// ---- async global->LDS 16B (lane i lands at ldsbase + i*16; ldsbase must be wave-uniform) ----
__device__ __forceinline__ void glld16(const void* gsrc, void* ldsbase) {
  __builtin_amdgcn_global_load_lds(
      (const __attribute__((address_space(1))) unsigned int*)gsrc,
      (__attribute__((address_space(3))) unsigned int*)(unsigned int)(unsigned long long)ldsbase,
      16, 0, 0);
}

// ---------------- fp32 -> bf16 elementwise ----------------
__global__ void cvt_f2b(const float* __restrict__ in, unsigned short* __restrict__ out, int n4) {
  int i = blockIdx.x * 256 + threadIdx.x;
  if (i >= n4) return;
  float4 v = ((const float4*)in)[i];
  ushort4 o;
  o.x = f2bf(v.x); o.y = f2bf(v.y); o.z = f2bf(v.z); o.w = f2bf(v.w);
  ((ushort4*)out)[i] = o;
}

// ---------------- fp32 [R][Cc] -> bf16 [Cc][R] transpose ----------------
__global__ void trans_f2b(const float* __restrict__ in, unsigned short* __restrict__ out, int R, int Cc) {
  __shared__ float tile[32][33];
  int c0 = blockIdx.x * 32, r0 = blockIdx.y * 32;
  int tx = threadIdx.x, ty = threadIdx.y;
  #pragma unroll
  for (int k = 0; k < 4; k++)
    tile[ty + 8*k][tx] = in[(size_t)(r0 + ty + 8*k) * Cc + c0 + tx];
  __syncthreads();
  #pragma unroll
  for (int k = 0; k < 4; k++)
    out[(size_t)(c0 + ty + 8*k) * R + r0 + tx] = f2bf(tile[tx][ty + 8*k]);
}

// ---------------- V slice transpose bf16 [s][h] -> [h][s] ----------------
__global__ void trans_v(const unsigned short* __restrict__ qkv, unsigned short* __restrict__ vT) {
  __shared__ unsigned short tile[32][33];
  int slice = blockIdx.z;           // b*4+kh
  int s0 = blockIdx.x * 32, h0 = blockIdx.y * 32;
  int tx = threadIdx.x, ty = threadIdx.y;
  const unsigned short* in = qkv + (size_t)(slice >> 2) * TT * QKVC + (NHC + KHC) + (slice & 3) * HD;
  unsigned short* out = vT + (size_t)slice * HD * TT;
  #pragma unroll
  for (int k = 0; k < 4; k++)
    tile[ty + 8*k][tx] = in[(size_t)(s0 + ty + 8*k) * QKVC + h0 + tx];
  __syncthreads();
  #pragma unroll
  for (int k = 0; k < 4; k++)
    out[(size_t)(h0 + ty + 8*k) * TT + s0 + tx] = tile[tx][ty + 8*k];
}

// ---------------- RoPE sin/cos table (fp64 precision) ----------------
__global__ void sincos_init(float* __restrict__ stab, float* __restrict__ ctab) {
  int idx = blockIdx.x * 256 + threadIdx.x;
  if (idx >= TT * 64) return;
  int t = idx >> 6, i = idx & 63;
  double inv = exp(-log(10000.0) * ((double)i / 64.0));
  double ang = (double)t * inv;
  stab[idx] = (float)sin(ang);
  ctab[idx] = (float)cos(ang);
}

// ---------------- NT GEMM 256x256 tile, BK=32, 8 waves, DEPTH-3 counted-vmcnt pipeline ----------------
// T4: 4 LDS buffers; prologue stages tiles 0..2; iteration t waits vmcnt(8)
// (tile t landed, tiles t+1/t+2 stay in flight ACROSS the barrier - never
// drain to 0 in the main loop), raw s_barrier, then stages t+3 and computes.
// T2: paired-row XOR swizzle (2 rows per 128B superrow; slot8 = ((r&1)<<2)|c,
// eff = slot8 ^ ((r>>1)&7)): fragment ds_read_b128 hits each 16B bank-slot
// exactly twice (2-way = free). glld16 source uses the bijective inverse.
// T1: XCD-aware flat block swizzle (both grids are %8==0).
template<int OUTBF16>
__global__ __launch_bounds__(512, 2) void gemm256(
    const unsigned short* __restrict__ A, const unsigned short* __restrict__ Bt,
    void* __restrict__ outp, int M, int Nn, int Kd) {
  __shared__ unsigned short As[4][256 * 32];   // 16 KiB per buf
  __shared__ unsigned short Bs[4][256 * 32];
  int tid = threadIdx.x;
  int wave = tid >> 6, lane = tid & 63, q4 = lane >> 4, l16 = lane & 15;

  int gx = Nn >> 8;
  int nwg = gridDim.x;
  int bid = blockIdx.x;
  int bid2 = (nwg & 7) ? bid : ((bid & 7) * (nwg >> 3) + (bid >> 3));
  int bx = bid2 % gx, by = bid2 / gx;
  int m0 = by * 256, n0 = bx * 256;

  int wm = (wave >> 2) * 128;      // 2 M-waves
  int wn = (wave & 3) * 64;        // 4 N-waves

  f32x4 acc[8][4];
  #pragma unroll
  for (int i = 0; i < 8; i++)
    #pragma unroll
    for (int j = 0; j < 4; j++) acc[i][j] = f32x4{0.f, 0.f, 0.f, 0.f};

  const unsigned short* Abase = A + (size_t)m0 * Kd;
  const unsigned short* Bbase = Bt + (size_t)n0 * Kd;

  // stage source geometry (per thread, 2 rounds per matrix):
  // LDS chunk L = rd*512 + wave*64 + lane; srow=L>>3, eff=L&7;
  // slot8 = eff ^ (srow&7); global row r = srow*2 + (slot8>>2); k-chunk cg = slot8&3.
  int sR[2], sCG[2], sBase[2];
  #pragma unroll
  for (int rd = 0; rd < 2; rd++) {
    int L = rd * 512 + wave * 64 + lane;
    int srow = L >> 3, eff = L & 7;
    int slot8 = eff ^ (srow & 7);
    sR[rd] = srow * 2 + (slot8 >> 2);
    sCG[rd] = slot8 & 3;
    sBase[rd] = (rd * 512 + wave * 64) * 8;   // wave-uniform LDS short offset
  }
  auto stage = [&](int kt, int buf) {
    const unsigned short* Ak = Abase + kt * 32;
    const unsigned short* Bk = Bbase + kt * 32;
    #pragma unroll
    for (int rd = 0; rd < 2; rd++)
      glld16(Ak + (size_t)sR[rd] * Kd + sCG[rd] * 8, &As[buf][sBase[rd]]);
    #pragma unroll
    for (int rd = 0; rd < 2; rd++)
      glld16(Bk + (size_t)sR[rd] * Kd + sCG[rd] * 8, &Bs[buf][sBase[rd]]);
  };

  // fragment read offsets (shorts), constant per thread:
  // chunk = (R>>1)*8 + ((((R&1)<<2)|q4) ^ ((R>>1)&7)); offset = chunk*8
  int aoffs[8], boffs[4];
  #pragma unroll
  for (int mf = 0; mf < 8; mf++) {
    int R = wm + mf * 16 + l16;
    int srow = R >> 1;
    aoffs[mf] = (srow * 8 + ((((R & 1) << 2) | q4) ^ (srow & 7))) * 8;
  }
  #pragma unroll
  for (int nf = 0; nf < 4; nf++) {
    int R = wn + nf * 16 + l16;
    int srow = R >> 1;
    boffs[nf] = (srow * 8 + ((((R & 1) << 2) | q4) ^ (srow & 7))) * 8;
  }

  int nkt = Kd >> 5;              // BK=32; nkt = 64 for both our calls
  stage(0, 0);
  stage(1, 1);
  stage(2, 2);

  for (int t = 0; t < nkt; t++) {
    int cur = t & 3;
    // counted wait BEFORE the barrier: my wave's tile-t loads landed,
    // tiles t+1/t+2 (8 loads) stay in flight across the barrier.
    if (t < nkt - 2)       asm volatile("s_waitcnt vmcnt(8)" ::: "memory");
    else if (t == nkt - 2) asm volatile("s_waitcnt vmcnt(4)" ::: "memory");
    else                   asm volatile("s_waitcnt vmcnt(0)" ::: "memory");
    asm volatile("s_barrier" ::: "memory");
    if (t + 3 < nkt) stage(t + 3, (t + 3) & 3);   // buf freed by the barrier

    s16x8 af[8], bfv[4];
    #pragma unroll
    for (int mf = 0; mf < 8; mf++) af[mf] = *(const s16x8*)&As[cur][aoffs[mf]];
    #pragma unroll
    for (int nf = 0; nf < 4; nf++) bfv[nf] = *(const s16x8*)&Bs[cur][boffs[nf]];
    __builtin_amdgcn_s_setprio(1);
    #pragma unroll
    for (int mf = 0; mf < 8; mf++)
      #pragma unroll
      for (int nf = 0; nf < 4; nf++)
        acc[mf][nf] = __builtin_amdgcn_mfma_f32_16x16x32_bf16(af[mf], bfv[nf], acc[mf][nf], 0, 0, 0);
    __builtin_amdgcn_s_setprio(0);
  }

  #pragma unroll
  for (int mf = 0; mf < 8; mf++)
    #pragma unroll
    for (int nf = 0; nf < 4; nf++)
      #pragma unroll
      for (int r = 0; r < 4; r++) {
        int row = m0 + wm + mf * 16 + q4 * 4 + r;
        int col = n0 + wn + nf * 16 + l16;
        float v = acc[mf][nf][r];
        if (OUTBF16) ((unsigned short*)outp)[(size_t)row * Nn + col] = f2bf(v);
        else         ((float*)outp)[(size_t)row * Nn + col] = v;
      }
}

// ---------------- RMSNorm + RoPE + scale ----------------
// NOTE: q scale folds in log2(e) so attention can use exp2 directly
// (softmax is exactly invariant: p = exp(S-m) = 2^(S*log2e - m*log2e)).
__global__ __launch_bounds__(256) void postproc(
    const unsigned short* __restrict__ qkv, unsigned short* __restrict__ qr,
    unsigned short* __restrict__ kr, const float* __restrict__ stab, const float* __restrict__ ctab) {
  __shared__ float sh[NHC + KHC];
  __shared__ float redq[4], redk[4];
  int row = blockIdx.x;
  int t = row & (TT - 1);
  int tid = threadIdx.x;
  const unsigned short* base = qkv + (size_t)row * QKVC;
  float sq = 0.f, sk = 0.f;
  uint4 qv = *(const uint4*)&base[tid * 8];
  const unsigned short* qp = (const unsigned short*)&qv;
  #pragma unroll
  for (int i = 0; i < 8; i++) { float f = bf2f(qp[i]); sh[tid*8 + i] = f; sq += f*f; }
  unsigned kv = *(const unsigned*)&base[NHC + tid*2];
  {
    float f0 = bf2f((unsigned short)(kv & 0xffff));
    float f1 = bf2f((unsigned short)(kv >> 16));
    sh[NHC + tid*2] = f0; sh[NHC + tid*2 + 1] = f1;
    sk += f0*f0 + f1*f1;
  }
  #pragma unroll
  for (int off = 32; off > 0; off >>= 1) { sq += __shfl_xor(sq, off); sk += __shfl_xor(sk, off); }
  if ((tid & 63) == 0) { redq[tid >> 6] = sq; redk[tid >> 6] = sk; }
  __syncthreads();
  float fq = rsqrtf((redq[0]+redq[1]+redq[2]+redq[3]) * (1.f/NHC) + 1e-6f)
             * (0.08838834764831845f * 1.4426950408889634f);
  float fk = rsqrtf((redk[0]+redk[1]+redk[2]+redk[3]) * (1.f/KHC) + 1e-6f);
  #pragma unroll
  for (int pi = 0; pi < 4; pi++) {
    int P = pi * 256 + tid;
    int head = P >> 6, i = P & 63;
    float s = stab[t*64 + i], c = ctab[t*64 + i];
    float x1 = sh[head*128 + i], x2 = sh[head*128 + i + 64];
    qr[(size_t)row * NHC + head*128 + i]      = f2bf((x1*c - x2*s) * fq);
    qr[(size_t)row * NHC + head*128 + i + 64] = f2bf((x2*c + x1*s) * fq);
  }
  {
    int head = tid >> 6, i = tid & 63;
    float s = stab[t*64 + i], c = ctab[t*64 + i];
    float x1 = sh[NHC + head*128 + i], x2 = sh[NHC + head*128 + i + 64];
    kr[(size_t)row * KHC + head*128 + i]      = f2bf((x1*c - x2*s) * fk);
    kr[(size_t)row * KHC + head*128 + i + 64] = f2bf((x2*c + x1*s) * fk);
  }
}

// ---------------- flash attention v4 (unchanged; 198-201us verified) ----------------
__global__ __launch_bounds__(256, 2) void attn(
    const unsigned short* __restrict__ qr, const unsigned short* __restrict__ kr,
    const unsigned short* __restrict__ vT, unsigned short* __restrict__ enc) {
  __shared__ unsigned short Ks[2][64 * 128];   // 16KB each; Ks[0]+Ks[1] holds Q in prologue
  __shared__ unsigned short Vs[2][128 * 64];   // 16KB each, layout [h][s-chunk]
  int tid = threadIdx.x;
  int wave = tid >> 6, lane = tid & 63, q4 = lane >> 4, l16 = lane & 15;
  int bid = blockIdx.x;
  int qt = bid & 15, n = (bid >> 4) & 15, b = bid >> 8, kh = n >> 2;

  const unsigned short* kbase = kr + ((size_t)(b * TT)) * KHC + kh * HD;
  const unsigned short* vbase = vT + ((size_t)((b * KVH + kh) * HD)) * TT;

  auto stageK = [&](int j, int kb) {
    const unsigned short* base = kbase + (size_t)(j * 64) * KHC;
    #pragma unroll
    for (int t = 0; t < 4; t++) {
      int L = wave * 4 + t;
      int r = L * 4 + (lane >> 4);
      int cg = (lane & 15) ^ (r & 7);
      glld16(base + (size_t)r * KHC + cg * 8, &Ks[kb][L * 512]);
    }
  };
  auto stageV = [&](int j, int vb) {
    const unsigned short* base = vbase + j * 64;
    #pragma unroll
    for (int t = 0; t < 4; t++) {
      int L = wave * 4 + t;
      int r = L * 8 + (lane >> 3);
      int cg = (lane & 7) ^ (r & 7);
      glld16(base + (size_t)r * TT + cg * 8, &Vs[vb][L * 512]);
    }
  };

  {
    const unsigned short* base = qr + ((size_t)(b * TT + qt * 128)) * NHC + n * HD;
    #pragma unroll
    for (int t = 0; t < 8; t++) {
      int L = wave * 8 + t;
      int r = L * 4 + (lane >> 4);
      int cg = (lane & 15) ^ (r & 7);
      glld16(base + (size_t)r * NHC + cg * 8, (unsigned short*)Ks + L * 512);
    }
  }
  stageV(0, 0);
  asm volatile("s_waitcnt vmcnt(0)" ::: "memory");
  __syncthreads();
  s16x8 qf[2][4];
  #pragma unroll
  for (int qb = 0; qb < 2; qb++)
    #pragma unroll
    for (int ku = 0; ku < 4; ku++) {
      int r = wave * 32 + qb * 16 + l16;
      qf[qb][ku] = *(const s16x8*)&((const unsigned short*)Ks)[r * 128 + (((ku * 4 + q4) ^ (r & 7)) << 3)];
    }
  __syncthreads();
  stageK(0, 0);
  asm volatile("s_waitcnt vmcnt(0)" ::: "memory");
  __syncthreads();

  float m_st[2] = {-1e30f, -1e30f}, l_st[2] = {0.f, 0.f};
  f32x4 O[2][8];
  #pragma unroll
  for (int qb = 0; qb < 2; qb++)
    #pragma unroll
    for (int hb = 0; hb < 8; hb++) O[qb][hb] = f32x4{0.f, 0.f, 0.f, 0.f};

  for (int j = 0; j < 32; j++) {
    int cur = j & 1;
    if (j < 31) { stageK(j + 1, cur ^ 1); stageV(j + 1, cur ^ 1); }
    f32x4 S[2][4];
    #pragma unroll
    for (int qb = 0; qb < 2; qb++)
      #pragma unroll
      for (int mb = 0; mb < 4; mb++) S[qb][mb] = f32x4{0.f, 0.f, 0.f, 0.f};
    __builtin_amdgcn_s_setprio(1);
    #pragma unroll
    for (int mb = 0; mb < 4; mb++) {
      int r = mb * 16 + l16;
      #pragma unroll
      for (int ku = 0; ku < 4; ku++) {
        s16x8 kf = *(const s16x8*)&Ks[cur][r * 128 + (((ku * 4 + q4) ^ (r & 7)) << 3)];
        S[0][mb] = __builtin_amdgcn_mfma_f32_16x16x32_bf16(kf, qf[0][ku], S[0][mb], 0, 0, 0);
        S[1][mb] = __builtin_amdgcn_mfma_f32_16x16x32_bf16(kf, qf[1][ku], S[1][mb], 0, 0, 0);
      }
    }
    __builtin_amdgcn_s_setprio(0);
    s16x8 pf8[2][2];
    #pragma unroll
    for (int qb = 0; qb < 2; qb++) {
      float mx = -1e30f;
      #pragma unroll
      for (int mb = 0; mb < 4; mb++)
        #pragma unroll
        for (int r = 0; r < 4; r++) mx = fmaxf(mx, S[qb][mb][r]);
      mx = fmaxf(mx, __shfl_xor(mx, 16));
      mx = fmaxf(mx, __shfl_xor(mx, 32));
      if (!__all(mx - m_st[qb] <= 8.f)) {
        float alpha = EXP2F(m_st[qb] - mx);
        m_st[qb] = mx;
        l_st[qb] *= alpha;
        #pragma unroll
        for (int hb = 0; hb < 8; hb++) O[qb][hb] *= alpha;
      }
      float mcur = m_st[qb];
      float rs = 0.f;
      #pragma unroll
      for (int mb = 0; mb < 4; mb++)
        #pragma unroll
        for (int r = 0; r < 4; r++) {
          float p = EXP2F(S[qb][mb][r] - mcur);
          rs += p;
          pf8[qb][mb >> 1][(mb & 1) * 4 + r] = (short)f2bf(p);
        }
      rs += __shfl_xor(rs, 16);
      rs += __shfl_xor(rs, 32);
      l_st[qb] += rs;
    }
    __builtin_amdgcn_s_setprio(1);
    #pragma unroll
    for (int su = 0; su < 2; su++) {
      #pragma unroll
      for (int hb = 0; hb < 8; hb++) {
        int r = hb * 16 + l16;
        int c0 = su * 8 + q4;
        int c1 = c0 + 4;
        s16x4 v0 = *(const s16x4*)&Vs[cur][r * 64 + (((c0 >> 1) ^ (r & 7)) << 3) + ((c0 & 1) << 2)];
        s16x4 v1 = *(const s16x4*)&Vs[cur][r * 64 + (((c1 >> 1) ^ (r & 7)) << 3) + ((c1 & 1) << 2)];
        s16x8 vf = __builtin_shufflevector(v0, v1, 0, 1, 2, 3, 4, 5, 6, 7);
        O[0][hb] = __builtin_amdgcn_mfma_f32_16x16x32_bf16(vf, pf8[0][su], O[0][hb], 0, 0, 0);
        O[1][hb] = __builtin_amdgcn_mfma_f32_16x16x32_bf16(vf, pf8[1][su], O[1][hb], 0, 0, 0);
      }
    }
    __builtin_amdgcn_s_setprio(0);
    asm volatile("s_waitcnt vmcnt(0)" ::: "memory");
    __syncthreads();
  }
  #pragma unroll
  for (int qb = 0; qb < 2; qb++) {
    float inv = 1.f / l_st[qb];
    int t = b * TT + qt * 128 + wave * 32 + qb * 16 + l16;
    #pragma unroll
    for (int hb = 0; hb < 8; hb++) {
      ushort4 o;
      o.x = f2bf(O[qb][hb][0] * inv);
      o.y = f2bf(O[qb][hb][1] * inv);
      o.z = f2bf(O[qb][hb][2] * inv);
      o.w = f2bf(O[qb][hb][3] * inv);
      *(ushort4*)&enc[(size_t)t * NHC + n * HD + hb * 16 + q4 * 4] = o;
    }
  }
}

extern "C" void kernel_launch(void* const* d_in, const int* in_sizes, int n_in,
                              void* d_out, int out_size, void* d_ws, size_t ws_size,
                              hipStream_t stream) {
  const float* x  = (const float*)d_in[0];
  const float* Wq = (const float*)d_in[1];
  const float* Wk = (const float*)d_in[2];
  const float* Wv = (const float*)d_in[3];
  const float* Wo = (const float*)d_in[4];
  float* out = (float*)d_out;

  char* ws = (char*)d_ws;
  size_t off = 0;
  auto alloc = [&](size_t bytes) -> void* {
    void* p = ws + off;
    off += (bytes + 255) & ~(size_t)255;
    return p;
  };
  unsigned short* xb    = (unsigned short*)alloc((size_t)BT * CC * 2);
  unsigned short* wqkvt = (unsigned short*)alloc((size_t)QKVC * CC * 2);
  unsigned short* wot   = (unsigned short*)alloc((size_t)CC * NHC * 2);
  unsigned short* qkv   = (unsigned short*)alloc((size_t)BT * QKVC * 2);
  unsigned short* qrb   = (unsigned short*)alloc((size_t)BT * NHC * 2);
  unsigned short* krb   = (unsigned short*)alloc((size_t)BT * KHC * 2);
  unsigned short* vTb   = (unsigned short*)alloc((size_t)BB * KVH * HD * TT * 2);
  unsigned short* encb  = (unsigned short*)alloc((size_t)BT * NHC * 2);
  float* stab = (float*)alloc((size_t)TT * 64 * 4);
  float* ctab = (float*)alloc((size_t)TT * 64 * 4);

  dim3 tb(32, 8);
  cvt_f2b<<<(BT*CC/4 + 255)/256, 256, 0, stream>>>(x, xb, BT*CC/4);
  trans_f2b<<<dim3(NHC/32, CC/32), tb, 0, stream>>>(Wq, wqkvt, CC, NHC);
  trans_f2b<<<dim3(KHC/32, CC/32), tb, 0, stream>>>(Wk, wqkvt + (size_t)NHC*CC, CC, KHC);
  trans_f2b<<<dim3(KHC/32, CC/32), tb, 0, stream>>>(Wv, wqkvt + (size_t)(NHC+KHC)*CC, CC, KHC);
  trans_f2b<<<dim3(NHC/32, NHC/32), tb, 0, stream>>>(Wo, wot, NHC, CC);
  sincos_init<<<(TT*64 + 255)/256, 256, 0, stream>>>(stab, ctab);
  gemm256<1><<<(BT/256) * (QKVC/256), 512, 0, stream>>>(xb, wqkvt, qkv, BT, QKVC, CC);
  postproc<<<BT, 256, 0, stream>>>(qkv, qrb, krb, stab, ctab);
  trans_v<<<dim3(TT/32, HD/32, BB*KVH), tb, 0, stream>>>(qkv, vTb);
  attn<<<BB * NHEAD * (TT/128), 256, 0, stream>>>(qrb, krb, vTb, encb);
  gemm256<0><<<(BT/256) * (CC/256), 512, 0, stream>>>(encb, wot, out, BT, CC, NHC);
}